// Round 10
// baseline (132.997 us; speedup 1.0000x reference)
//
#include <hip/hip_runtime.h>

#define L_LEN 4096
#define NT 512
#define ROWS 512               // B*J = 32*16 fixed by the reference
#define SLOP 48u               // f32-key error band (actual error <= ~4 ulps; 12x margin)
#define BCAP 512
#define BSKIP (BCAP - 64)      // take bin-wide band only if bin population <= this

__global__ __launch_bounds__(NT) void AttentionEssentialReinforce_51238959841470_kernel(
    const int* __restrict__ ids,       // int32 OR little-endian int64 (auto-detected)
    const float* __restrict__ amask,   // (ROWS, 2*L), only first half used
    const float* __restrict__ uin,     // (ROWS, L)
    float* __restrict__ out,           // float32: [ids | mask | -mask], n_per each
    int n_per)
{
    __shared__ unsigned int hist[4096];          // 16 KB
    __shared__ unsigned int s_wtot[8], s_woff[8];
    __shared__ unsigned long long bkey[BCAP];    // band: exact f64 keys (4 KB)
    __shared__ int bidx[BCAP];                   // band: element indices (2 KB)
    __shared__ unsigned int s_or, s_prefix, s_remk, s_csel, s_nhi, s_bn;

    const int row = blockIdx.x;
    const int tid = threadIdx.x;
    const int lane = tid & 63, wid = tid >> 6;
    const float* wrow = amask + (size_t)row * (2 * L_LEN);
    const float* urow = uin + (size_t)row * L_LEN;

    // Issue input loads immediately (latency overlaps LDS zeroing below).
    float4 a0 = reinterpret_cast<const float4*>(wrow)[tid];
    float4 a1 = reinterpret_cast<const float4*>(wrow)[NT + tid];
    float4 b0 = reinterpret_cast<const float4*>(urow)[tid];
    float4 b1 = reinterpret_cast<const float4*>(urow)[NT + tid];

    if (tid == 0) { s_or = 0; s_nhi = 0; s_bn = 0; }
    // zero 4096 bins with uint4 stores (2 per thread)
    {
        uint4 z = make_uint4(0, 0, 0, 0);
        reinterpret_cast<uint4*>(hist)[tid] = z;
        reinterpret_cast<uint4*>(hist)[NT + tid] = z;
    }
    // int64-vs-int32 id detection: LE int64 ids (<2^31) have all-zero odd words.
    if (((const unsigned*)ids)[2 * tid + 1] != 0u) s_or = 1u;   // benign race
    __syncthreads();                                            // B1

    // ---- Phase 1: f32 keys in registers + pass-0 histogram (12-bit, bits 31:20).
    // r = max(w,1e-30)/(-ln u) is monotone-equivalent to log(max(w,1e-30))+gumbel(u);
    // positive-float IEEE bits are order-isomorphic to value. All w>0 keys are >= 1;
    // w<=0 keys are exactly 0 and skip the histogram, so cnt == sum(hist).
    float wv[8] = {a0.x, a0.y, a0.z, a0.w, a1.x, a1.y, a1.z, a1.w};
    float uv[8] = {b0.x, b0.y, b0.z, b0.w, b1.x, b1.y, b1.z, b1.w};
    unsigned key[8];
    #pragma unroll
    for (int e = 0; e < 8; ++e) {
        key[e] = 0u;
        if (wv[e] > 0.0f) {
            float t = -logf(uv[e]);
            float r = fmaxf(wv[e], 1e-30f) / t;
            key[e] = __float_as_uint(r);
            atomicAdd(&hist[key[e] >> 20], 1u);
        }
    }
    const bool is64 = (s_or == 0u);        // safe: read-after-write same thread? no —
                                           // raced flag, but only transitions 0->1 and
                                           // was written before B1 by all threads.
    // Prefetch ids: latency overlaps the scan below.
    int ida[8];
    if (!is64) {
        const int4* idr = reinterpret_cast<const int4*>(ids + (size_t)row * L_LEN);
        int4 t0 = idr[tid], t1 = idr[NT + tid];
        ida[0]=t0.x; ida[1]=t0.y; ida[2]=t0.z; ida[3]=t0.w;
        ida[4]=t1.x; ida[5]=t1.y; ida[6]=t1.z; ida[7]=t1.w;
    } else {
        const longlong2* idr = reinterpret_cast<const longlong2*>(
            (const long long*)ids + (size_t)row * L_LEN);
        longlong2 a = idr[2 * tid], b = idr[2 * tid + 1];
        longlong2 c = idr[2 * (NT + tid)], d = idr[2 * (NT + tid) + 1];
        ida[0]=(int)a.x; ida[1]=(int)a.y; ida[2]=(int)b.x; ida[3]=(int)b.y;
        ida[4]=(int)c.x; ida[5]=(int)c.y; ida[6]=(int)d.x; ida[7]=(int)d.y;
    }
    __syncthreads();                                            // B2

    // ---- Phase 2: descending suffix scan over 4096 bins ----
    int b0i = 4095 - 8 * tid;                    // 8 descending bins per thread
    unsigned c[8], lsum = 0;
    #pragma unroll
    for (int m = 0; m < 8; ++m) { c[m] = hist[b0i - m]; lsum += c[m]; }
    unsigned scan = lsum;
    #pragma unroll
    for (int off = 1; off < 64; off <<= 1) {
        unsigned o = __shfl_up(scan, (unsigned)off, 64);
        if (lane >= off) scan += o;
    }
    if (lane == 63) s_wtot[wid] = scan;
    __syncthreads();                                            // B3
    if (tid < 8) {
        unsigned acc = 0;
        for (int w2 = 0; w2 < tid; ++w2) acc += s_wtot[w2];
        s_woff[tid] = acc;
    }
    __syncthreads();                                            // B4

    // cnt for free from the histogram: total = s_woff[7] + s_wtot[7]
    const int cnt = (int)(s_woff[7] + s_wtot[7]);
    const int k = (int)floorf(0.15f * (float)cnt);   // f32(0.15)*f32(cnt), floored (as np)

    unsigned lo_thr = 0xFFFFFFFFu, hi_thr = 0xFFFFFFFFu;   // k==0: select none
    int need = 0;
    unsigned bn = 0;

    if (k > 0) {
        unsigned run = s_woff[wid] + (scan - lsum);  // keys in strictly-higher bins
        unsigned remk = (unsigned)k;
        #pragma unroll
        for (int m = 0; m < 8; ++m) {
            if (run < remk && run + c[m] >= remk) {  // exactly one (thread,m) hits
                s_prefix = (unsigned)(b0i - m);
                s_remk = remk - run;
                s_csel = c[m];
            }
            run += c[m];
        }
    }
    __syncthreads();                                            // B5

    if (k > 0) {
        unsigned T12 = s_prefix, remk = s_remk, csel = s_csel;
        unsigned B_lo, B_hi;
        if (csel <= BSKIP) {
            // Expected path: band = whole 12-bit bin +- SLOP (no refine pass).
            B_lo = T12 << 20;
            B_hi = (T12 << 20) | 0xFFFFFu;
        } else {
            // Rare fallback: one 8-bit refine pass (bits 19:12) to shrink the band.
            if (tid < 256) hist[tid] = 0;
            __syncthreads();
            #pragma unroll
            for (int e = 0; e < 8; ++e)
                if ((key[e] >> 20) == T12)
                    atomicAdd(&hist[(key[e] >> 12) & 0xFFu], 1u);
            __syncthreads();
            if (tid < 64) {
                unsigned cc[4], ls = 0;
                #pragma unroll
                for (int m = 0; m < 4; ++m) { cc[m] = hist[255 - 4 * tid - m]; ls += cc[m]; }
                unsigned sc = ls;
                #pragma unroll
                for (int off = 1; off < 64; off <<= 1) {
                    unsigned o = __shfl_up(sc, (unsigned)off, 64);
                    if (tid >= off) sc += o;
                }
                unsigned rn = sc - ls;
                #pragma unroll
                for (int m = 0; m < 4; ++m) {
                    if (rn < remk && rn + cc[m] >= remk)
                        s_prefix = (T12 << 8) | (unsigned)(255 - 4 * tid - m);
                    rn += cc[m];
                }
            }
            __syncthreads();
            unsigned T20 = s_prefix;
            B_lo = T20 << 12;
            B_hi = (T20 << 12) | 0xFFFu;
        }

        lo_thr = (B_lo > SLOP) ? B_lo - SLOP : 1u;   // >=1 excludes w<=0 sentinels
        hi_thr = B_hi + SLOP;                        // no overflow (keys <= 0x7F800000)

        // Collect band (exact f64 keys) + count certainly-selected
        unsigned nhi = 0;
        #pragma unroll
        for (int e = 0; e < 8; ++e) {
            if (key[e] > hi_thr) {
                nhi++;
            } else if (key[e] >= lo_thr) {
                unsigned pos = atomicAdd(&s_bn, 1u);
                if (pos < BCAP) {
                    double t = -log((double)uv[e]);
                    double r = (double)fmaxf(wv[e], 1e-30f) / t;
                    bkey[pos] = (unsigned long long)__double_as_longlong(r);
                    bidx[pos] = 4 * ((e >> 2) * NT + tid) + (e & 3);
                }
            }
        }
        unsigned nv = nhi;
        #pragma unroll
        for (int off = 32; off > 0; off >>= 1) nv += __shfl_down(nv, off, 64);
        if (lane == 0) atomicAdd(&s_nhi, nv);
    }
    __syncthreads();                                            // B6

    if (k > 0) {
        need = k - (int)s_nhi;                       // >= 1 by construction
        bn = s_bn; if (bn > BCAP) bn = BCAP;
    }

    // ---- Phase 3: selection + float32 outputs ----
    const size_t obase = (size_t)row * L_LEN;
    float* o0 = out + obase;                      // masked ids
    float* o1 = out + (size_t)n_per + obase;      // mask
    float* o2 = out + 2 * (size_t)n_per + obase;  // -mask

    float f0[8], f1[8], f2[8];
    #pragma unroll
    for (int e = 0; e < 8; ++e) {
        bool sel;
        if (key[e] > hi_thr) {
            sel = true;
        } else if (key[e] < lo_thr) {
            sel = false;
        } else {
            // band member: rank by (f64 key desc, index asc) — stable, exact
            double t = -log((double)uv[e]);
            double r = (double)fmaxf(wv[e], 1e-30f) / t;
            unsigned long long myk = (unsigned long long)__double_as_longlong(r);
            int myi = 4 * ((e >> 2) * NT + tid) + (e & 3);
            int rnk = 0;
            for (unsigned j = 0; j < bn; ++j)
                rnk += (bkey[j] > myk) || (bkey[j] == myk && bidx[j] < myi);
            sel = (rnk < need);
        }
        f0[e] = sel ? 103.0f : (float)ida[e];
        f1[e] = sel ? 1.0f : 0.0f;
        f2[e] = sel ? -1.0f : -0.0f;
    }
    reinterpret_cast<float4*>(o0)[tid]      = make_float4(f0[0], f0[1], f0[2], f0[3]);
    reinterpret_cast<float4*>(o0)[NT + tid] = make_float4(f0[4], f0[5], f0[6], f0[7]);
    reinterpret_cast<float4*>(o1)[tid]      = make_float4(f1[0], f1[1], f1[2], f1[3]);
    reinterpret_cast<float4*>(o1)[NT + tid] = make_float4(f1[4], f1[5], f1[6], f1[7]);
    reinterpret_cast<float4*>(o2)[tid]      = make_float4(f2[0], f2[1], f2[2], f2[3]);
    reinterpret_cast<float4*>(o2)[NT + tid] = make_float4(f2[4], f2[5], f2[6], f2[7]);
}

extern "C" void kernel_launch(void* const* d_in, const int* in_sizes, int n_in,
                              void* d_out, int out_size, void* d_ws, size_t ws_size,
                              hipStream_t stream) {
    const int*   ids   = (const int*)d_in[0];     // (B,J,L) ids (int32/int64 auto-detect)
    const float* amask = (const float*)d_in[1];   // (B,J,2L) float32
    const float* uin   = (const float*)d_in[2];   // (B,J,L) float32
    float* out = (float*)d_out;                   // float32 x (3 * B*J*L)

    const int n_per = ROWS * L_LEN;               // 2,097,152 (hardcoded geometry)

    AttentionEssentialReinforce_51238959841470_kernel<<<dim3(ROWS), dim3(NT), 0, stream>>>(
        ids, amask, uin, out, n_per);
}

// Round 11
// 131.788 us; speedup vs baseline: 1.0092x; 1.0092x over previous
//
#include <hip/hip_runtime.h>

#define L_LEN 4096
#define NT 512
#define ROWS 512               // B*J = 32*16 fixed by the reference
#define SLOP 48u               // f32-key error band (actual error <= ~4 ulps; 12x margin)
#define BCAP 512
#define BSKIP (BCAP - 64)      // take bin-wide band only if bin population <= this

// __launch_bounds__(512, 4): 4 waves/EU target => VGPR cap 128, 2 blocks/CU.
// R10 shipped without the 2nd arg and the allocator picked VGPR=32 -> scratch
// spills of the per-thread arrays -> 62 us (3x regression). Do not remove.
__global__ __launch_bounds__(NT, 4) void AttentionEssentialReinforce_51238959841470_kernel(
    const int* __restrict__ ids,       // int32 OR little-endian int64 (auto-detected)
    const float* __restrict__ amask,   // (ROWS, 2*L), only first half used
    const float* __restrict__ uin,     // (ROWS, L)
    float* __restrict__ out,           // float32: [ids | mask | -mask], n_per each
    int n_per)
{
    __shared__ unsigned int hist[4096];          // 16 KB
    __shared__ unsigned int s_wtot[8], s_woff[8];
    __shared__ unsigned long long bkey[BCAP];    // band: exact f64 keys (4 KB)
    __shared__ int bidx[BCAP];                   // band: element indices (2 KB)
    __shared__ unsigned int s_or, s_prefix, s_remk, s_csel, s_nhi, s_bn;

    const int row = blockIdx.x;
    const int tid = threadIdx.x;
    const int lane = tid & 63, wid = tid >> 6;
    const float* wrow = amask + (size_t)row * (2 * L_LEN);
    const float* urow = uin + (size_t)row * L_LEN;

    // Issue w/u input loads immediately (latency overlaps LDS zeroing below).
    float4 a0 = reinterpret_cast<const float4*>(wrow)[tid];
    float4 a1 = reinterpret_cast<const float4*>(wrow)[NT + tid];
    float4 b0 = reinterpret_cast<const float4*>(urow)[tid];
    float4 b1 = reinterpret_cast<const float4*>(urow)[NT + tid];
    const unsigned iddet = ((const unsigned*)ids)[2 * tid + 1];

    if (tid == 0) { s_or = 0; s_nhi = 0; s_bn = 0; }
    {   // zero 4096 bins with uint4 stores (2 per thread)
        uint4 z = make_uint4(0, 0, 0, 0);
        reinterpret_cast<uint4*>(hist)[tid] = z;
        reinterpret_cast<uint4*>(hist)[NT + tid] = z;
    }
    // int64-vs-int32 id detection: LE int64 ids (<2^31) have all-zero odd words.
    if (iddet != 0u) s_or = 1u;                                 // benign race
    __syncthreads();                                            // B1

    // ---- Phase 1: f32 keys in registers + pass-0 histogram (12-bit, bits 31:20).
    // r = max(w,1e-30)/(-ln u) is monotone-equivalent to log(max(w,1e-30))+gumbel(u);
    // positive-float IEEE bits are order-isomorphic to value. All w>0 keys are >= 1;
    // w<=0 keys are exactly 0 and skip the histogram, so cnt == sum(hist).
    float wv[8] = {a0.x, a0.y, a0.z, a0.w, a1.x, a1.y, a1.z, a1.w};
    float uv[8] = {b0.x, b0.y, b0.z, b0.w, b1.x, b1.y, b1.z, b1.w};
    unsigned key[8];
    #pragma unroll
    for (int e = 0; e < 8; ++e) {
        key[e] = 0u;
        if (wv[e] > 0.0f) {
            float t = -logf(uv[e]);
            float r = fmaxf(wv[e], 1e-30f) / t;
            key[e] = __float_as_uint(r);
            atomicAdd(&hist[key[e] >> 20], 1u);
        }
    }
    const bool is64 = (s_or == 0u);              // read after B1: safe
    __syncthreads();                                            // B2

    // ---- Phase 2: descending suffix scan over 4096 bins ----
    int b0i = 4095 - 8 * tid;                    // 8 descending bins per thread
    unsigned c[8], lsum = 0;
    #pragma unroll
    for (int m = 0; m < 8; ++m) { c[m] = hist[b0i - m]; lsum += c[m]; }
    unsigned scan = lsum;
    #pragma unroll
    for (int off = 1; off < 64; off <<= 1) {
        unsigned o = __shfl_up(scan, (unsigned)off, 64);
        if (lane >= off) scan += o;
    }
    if (lane == 63) s_wtot[wid] = scan;
    __syncthreads();                                            // B3
    if (tid < 8) {
        unsigned acc = 0;
        for (int w2 = 0; w2 < tid; ++w2) acc += s_wtot[w2];
        s_woff[tid] = acc;
    }
    __syncthreads();                                            // B4

    // cnt for free from the histogram: total = s_woff[7] + s_wtot[7]
    const int cnt = (int)(s_woff[7] + s_wtot[7]);
    const int k = (int)floorf(0.15f * (float)cnt);   // f32(0.15)*f32(cnt), floored (as np)

    unsigned lo_thr = 0xFFFFFFFFu, hi_thr = 0xFFFFFFFFu;   // k==0: select none
    int need = 0;
    unsigned bn = 0;

    if (k > 0) {
        unsigned run = s_woff[wid] + (scan - lsum);  // keys in strictly-higher bins
        unsigned remk = (unsigned)k;
        #pragma unroll
        for (int m = 0; m < 8; ++m) {
            if (run < remk && run + c[m] >= remk) {  // exactly one (thread,m) hits
                s_prefix = (unsigned)(b0i - m);
                s_remk = remk - run;
                s_csel = c[m];
            }
            run += c[m];
        }
    }
    __syncthreads();                                            // B5

    if (k > 0) {
        unsigned T12 = s_prefix, remk = s_remk, csel = s_csel;
        unsigned B_lo, B_hi;
        if (csel <= BSKIP) {
            // Expected path: band = whole 12-bit bin +- SLOP (no refine pass).
            B_lo = T12 << 20;
            B_hi = (T12 << 20) | 0xFFFFFu;
        } else {
            // Rare fallback: one 8-bit refine pass (bits 19:12) to shrink the band.
            if (tid < 256) hist[tid] = 0;
            __syncthreads();
            #pragma unroll
            for (int e = 0; e < 8; ++e)
                if ((key[e] >> 20) == T12)
                    atomicAdd(&hist[(key[e] >> 12) & 0xFFu], 1u);
            __syncthreads();
            if (tid < 64) {
                unsigned cc[4], ls = 0;
                #pragma unroll
                for (int m = 0; m < 4; ++m) { cc[m] = hist[255 - 4 * tid - m]; ls += cc[m]; }
                unsigned sc = ls;
                #pragma unroll
                for (int off = 1; off < 64; off <<= 1) {
                    unsigned o = __shfl_up(sc, (unsigned)off, 64);
                    if (tid >= off) sc += o;
                }
                unsigned rn = sc - ls;
                #pragma unroll
                for (int m = 0; m < 4; ++m) {
                    if (rn < remk && rn + cc[m] >= remk)
                        s_prefix = (T12 << 8) | (unsigned)(255 - 4 * tid - m);
                    rn += cc[m];
                }
            }
            __syncthreads();
            unsigned T20 = s_prefix;
            B_lo = T20 << 12;
            B_hi = (T20 << 12) | 0xFFFu;
        }

        lo_thr = (B_lo > SLOP) ? B_lo - SLOP : 1u;   // >=1 excludes w<=0 sentinels
        hi_thr = B_hi + SLOP;                        // no overflow (keys <= 0x7F800000)

        // Collect band (exact f64 keys) + count certainly-selected
        unsigned nhi = 0;
        #pragma unroll
        for (int e = 0; e < 8; ++e) {
            if (key[e] > hi_thr) {
                nhi++;
            } else if (key[e] >= lo_thr) {
                unsigned pos = atomicAdd(&s_bn, 1u);
                if (pos < BCAP) {
                    double t = -log((double)uv[e]);
                    double r = (double)fmaxf(wv[e], 1e-30f) / t;
                    bkey[pos] = (unsigned long long)__double_as_longlong(r);
                    bidx[pos] = 4 * ((e >> 2) * NT + tid) + (e & 3);
                }
            }
        }
        unsigned nv = nhi;
        #pragma unroll
        for (int off = 32; off > 0; off >>= 1) nv += __shfl_down(nv, off, 64);
        if (lane == 0) atomicAdd(&s_nhi, nv);
    }
    __syncthreads();                                            // B6

    if (k > 0) {
        need = k - (int)s_nhi;                       // >= 1 by construction
        bn = s_bn; if (bn > BCAP) bn = BCAP;
    }

    // ---- Phase 3: ids load here (short live range; L2-resident, latency hidden
    // by selection math) + selection + float32 outputs ----
    const size_t obase = (size_t)row * L_LEN;
    float* o0 = out + obase;                      // masked ids
    float* o1 = out + (size_t)n_per + obase;      // mask
    float* o2 = out + 2 * (size_t)n_per + obase;  // -mask

    int ida[8];
    if (!is64) {
        const int4* idr = reinterpret_cast<const int4*>(ids + (size_t)row * L_LEN);
        int4 t0 = idr[tid], t1 = idr[NT + tid];
        ida[0]=t0.x; ida[1]=t0.y; ida[2]=t0.z; ida[3]=t0.w;
        ida[4]=t1.x; ida[5]=t1.y; ida[6]=t1.z; ida[7]=t1.w;
    } else {
        const longlong2* idr = reinterpret_cast<const longlong2*>(
            (const long long*)ids + (size_t)row * L_LEN);
        longlong2 a = idr[2 * tid], b = idr[2 * tid + 1];
        longlong2 c2 = idr[2 * (NT + tid)], d = idr[2 * (NT + tid) + 1];
        ida[0]=(int)a.x; ida[1]=(int)a.y; ida[2]=(int)b.x; ida[3]=(int)b.y;
        ida[4]=(int)c2.x; ida[5]=(int)c2.y; ida[6]=(int)d.x; ida[7]=(int)d.y;
    }

    float f0[8], f1[8], f2[8];
    #pragma unroll
    for (int e = 0; e < 8; ++e) {
        bool sel;
        if (key[e] > hi_thr) {
            sel = true;
        } else if (key[e] < lo_thr) {
            sel = false;
        } else {
            // band member: rank by (f64 key desc, index asc) — stable, exact
            double t = -log((double)uv[e]);
            double r = (double)fmaxf(wv[e], 1e-30f) / t;
            unsigned long long myk = (unsigned long long)__double_as_longlong(r);
            int myi = 4 * ((e >> 2) * NT + tid) + (e & 3);
            int rnk = 0;
            for (unsigned j = 0; j < bn; ++j)
                rnk += (bkey[j] > myk) || (bkey[j] == myk && bidx[j] < myi);
            sel = (rnk < need);
        }
        f0[e] = sel ? 103.0f : (float)ida[e];
        f1[e] = sel ? 1.0f : 0.0f;
        f2[e] = sel ? -1.0f : -0.0f;
    }
    reinterpret_cast<float4*>(o0)[tid]      = make_float4(f0[0], f0[1], f0[2], f0[3]);
    reinterpret_cast<float4*>(o0)[NT + tid] = make_float4(f0[4], f0[5], f0[6], f0[7]);
    reinterpret_cast<float4*>(o1)[tid]      = make_float4(f1[0], f1[1], f1[2], f1[3]);
    reinterpret_cast<float4*>(o1)[NT + tid] = make_float4(f1[4], f1[5], f1[6], f1[7]);
    reinterpret_cast<float4*>(o2)[tid]      = make_float4(f2[0], f2[1], f2[2], f2[3]);
    reinterpret_cast<float4*>(o2)[NT + tid] = make_float4(f2[4], f2[5], f2[6], f2[7]);
}

extern "C" void kernel_launch(void* const* d_in, const int* in_sizes, int n_in,
                              void* d_out, int out_size, void* d_ws, size_t ws_size,
                              hipStream_t stream) {
    const int*   ids   = (const int*)d_in[0];     // (B,J,L) ids (int32/int64 auto-detect)
    const float* amask = (const float*)d_in[1];   // (B,J,2L) float32
    const float* uin   = (const float*)d_in[2];   // (B,J,L) float32
    float* out = (float*)d_out;                   // float32 x (3 * B*J*L)

    const int n_per = ROWS * L_LEN;               // 2,097,152 (hardcoded geometry)

    AttentionEssentialReinforce_51238959841470_kernel<<<dim3(ROWS), dim3(NT), 0, stream>>>(
        ids, amask, uin, out, n_per);
}

// Round 12
// 87.108 us; speedup vs baseline: 1.5268x; 1.5129x over previous
//
#include <hip/hip_runtime.h>

#define L_LEN 4096
#define NT 512
#define ROWS 512               // B*J = 32*16 fixed by the reference
#define SLOP 48u               // f32-key error band (actual error <= ~4 ulps; 12x margin)
#define BCAP 256

// RE-ANCHOR: byte-equivalent to the kernel that benched dur_us=87.26 (round 9).
// The round-9/10 restructures (fused hist+logf loop, hoisted loads, conditional
// refine with in-branch barriers, cnt-from-hist) triggered a codegen cliff:
// kernel 21 us -> 62 us, VGPR_Count 20 -> 32, unaffected by __launch_bounds__.
// Do not reapply those deltas together; one at a time only.
__global__ __launch_bounds__(NT) void AttentionEssentialReinforce_51238959841470_kernel(
    const int* __restrict__ ids,       // int32 OR little-endian int64 (auto-detected)
    const float* __restrict__ amask,   // (ROWS, 2*L), only first half used
    const float* __restrict__ uin,     // (ROWS, L)
    float* __restrict__ out,           // float32: [ids | mask | -mask], n_per each
    int n_per)
{
    __shared__ unsigned int hist[4096];          // 16 KB (pass 0: 12-bit bins)
    __shared__ unsigned int s_wtot[8], s_woff[8];
    __shared__ unsigned long long bkey[BCAP];    // band: exact f64 keys
    __shared__ int bidx[BCAP];                   // band: element indices
    __shared__ unsigned int s_cnt, s_or, s_remk, s_prefix, s_nhi, s_bn;

    const int row = blockIdx.x;
    const int tid = threadIdx.x;
    const int lane = tid & 63, wid = tid >> 6;
    const float* wrow = amask + (size_t)row * (2 * L_LEN);
    const float* urow = uin + (size_t)row * L_LEN;

    if (tid == 0) { s_cnt = 0; s_or = 0; s_nhi = 0; s_bn = 0; }
    __syncthreads();

    // int64-vs-int32 id detection: LE int64 ids (<2^31) have all-zero odd words.
    if (((const unsigned*)ids)[2 * tid + 1] != 0u) s_or = 1u;   // benign race

    // ---- Phase 1: f32 keys in registers. r = max(w,1e-30)/(-ln u) is monotone-
    // equivalent to log(max(w,1e-30))+gumbel(u); positive-float IEEE bits are
    // order-isomorphic to value. (u==1 -> r=+inf-like top key, matching reference.)
    float wv[8], uv[8];
    {
        float4 a0 = reinterpret_cast<const float4*>(wrow)[tid];
        float4 a1 = reinterpret_cast<const float4*>(wrow)[NT + tid];
        float4 b0 = reinterpret_cast<const float4*>(urow)[tid];
        float4 b1 = reinterpret_cast<const float4*>(urow)[NT + tid];
        wv[0]=a0.x; wv[1]=a0.y; wv[2]=a0.z; wv[3]=a0.w;
        wv[4]=a1.x; wv[5]=a1.y; wv[6]=a1.z; wv[7]=a1.w;
        uv[0]=b0.x; uv[1]=b0.y; uv[2]=b0.z; uv[3]=b0.w;
        uv[4]=b1.x; uv[5]=b1.y; uv[6]=b1.z; uv[7]=b1.w;
    }
    unsigned key[8];
    unsigned localnz = 0;
    #pragma unroll
    for (int e = 0; e < 8; ++e) {
        key[e] = 0u;                                  // w<=0 -> bottom, never selected
        if (wv[e] > 0.0f) {
            float t = -logf(uv[e]);
            float r = fmaxf(wv[e], 1e-30f) / t;
            key[e] = __float_as_uint(r);
            localnz++;
        }
    }
    unsigned v = localnz;
    #pragma unroll
    for (int off = 32; off > 0; off >>= 1) v += __shfl_down(v, off, 64);
    if (lane == 0) atomicAdd(&s_cnt, v);
    __syncthreads();

    const bool is64 = (s_or == 0u);
    const int cnt = (int)s_cnt;
    const int k = (int)floorf(0.15f * (float)cnt);    // f32(0.15)*f32(cnt), floored (as np)

    // Prefetch ids now: L2 latency overlaps the radix passes below.
    int ida[8];
    if (!is64) {
        const int4* idr = reinterpret_cast<const int4*>(ids + (size_t)row * L_LEN);
        int4 t0 = idr[tid], t1 = idr[NT + tid];
        ida[0]=t0.x; ida[1]=t0.y; ida[2]=t0.z; ida[3]=t0.w;
        ida[4]=t1.x; ida[5]=t1.y; ida[6]=t1.z; ida[7]=t1.w;
    } else {
        const longlong2* idr = reinterpret_cast<const longlong2*>(
            (const long long*)ids + (size_t)row * L_LEN);
        longlong2 a = idr[2 * tid], b = idr[2 * tid + 1];
        longlong2 c = idr[2 * (NT + tid)], d = idr[2 * (NT + tid) + 1];
        ida[0]=(int)a.x; ida[1]=(int)a.y; ida[2]=(int)b.x; ida[3]=(int)b.y;
        ida[4]=(int)c.x; ida[5]=(int)c.y; ida[6]=(int)d.x; ida[7]=(int)d.y;
    }

    unsigned lo_thr = 0xFFFFFFFFu, hi_thr = 0xFFFFFFFFu;   // k==0: select none
    int need = 0;
    unsigned bn = 0;

    if (k > 0) {
        // ---- Phase 2: localize the k-th largest f32 key to its 20-bit-prefix bin.
        // Pass 0: 12-bit field (bits 31:20), 4096 bins.
        for (int b = tid; b < 4096; b += NT) hist[b] = 0;
        __syncthreads();
        #pragma unroll
        for (int e = 0; e < 8; ++e) atomicAdd(&hist[key[e] >> 20], 1u);
        __syncthreads();
        {
            int b0 = 4095 - 8 * tid;                 // 8 descending bins per thread
            unsigned c[8], lsum = 0;
            #pragma unroll
            for (int m = 0; m < 8; ++m) { c[m] = hist[b0 - m]; lsum += c[m]; }
            unsigned scan = lsum;
            #pragma unroll
            for (int off = 1; off < 64; off <<= 1) {
                unsigned o = __shfl_up(scan, (unsigned)off, 64);
                if (lane >= off) scan += o;
            }
            if (lane == 63) s_wtot[wid] = scan;
            __syncthreads();
            if (tid < 8) {
                unsigned acc = 0;
                for (int w2 = 0; w2 < tid; ++w2) acc += s_wtot[w2];
                s_woff[tid] = acc;
            }
            __syncthreads();
            unsigned run = s_woff[wid] + (scan - lsum);   // count in strictly-higher bins
            unsigned remk = (unsigned)k;
            #pragma unroll
            for (int m = 0; m < 8; ++m) {
                if (run < remk && run + c[m] >= remk) {   // exactly one (thread,m) hits
                    s_prefix = (unsigned)(b0 - m);
                    s_remk = remk - run;
                }
                run += c[m];
            }
        }
        __syncthreads();
        unsigned prefix12 = s_prefix;
        unsigned remk = s_remk;

        // Pass 1: 8-bit field (bits 19:12), 256 bins, keys matching prefix12 only.
        if (tid < 256) hist[tid] = 0;
        __syncthreads();
        #pragma unroll
        for (int e = 0; e < 8; ++e)
            if ((key[e] >> 20) == prefix12)
                atomicAdd(&hist[(key[e] >> 12) & 0xFFu], 1u);
        __syncthreads();
        if (tid < 64) {                              // wave 0: descending-bin scan
            unsigned c[4], lsum = 0;
            #pragma unroll
            for (int m = 0; m < 4; ++m) { c[m] = hist[255 - 4 * tid - m]; lsum += c[m]; }
            unsigned scan = lsum;
            #pragma unroll
            for (int off = 1; off < 64; off <<= 1) {
                unsigned o = __shfl_up(scan, (unsigned)off, 64);
                if (tid >= off) scan += o;
            }
            unsigned run = scan - lsum;
            #pragma unroll
            for (int m = 0; m < 4; ++m) {
                if (run < remk && run + c[m] >= remk) {
                    s_prefix = (prefix12 << 8) | (unsigned)(255 - 4 * tid - m);
                }
                run += c[m];
            }
        }
        __syncthreads();
        const unsigned T20 = s_prefix;               // k-th key's 20-bit prefix
        const unsigned B_lo = T20 << 12, B_hi = (T20 << 12) | 0xFFFu;

        // ---- Error band: [B_lo - SLOP, B_hi + SLOP]. key > hi => certainly top-k;
        // key < lo => certainly not; band resolved exactly in f64 below.
        lo_thr = (B_lo > SLOP) ? B_lo - SLOP : 1u;   // >=1 excludes w<=0 sentinels
        hi_thr = B_hi + SLOP;                        // no overflow (keys <= 0x7F800000)
        unsigned nhi = 0;
        #pragma unroll
        for (int e = 0; e < 8; ++e) {
            if (key[e] > hi_thr) {
                nhi++;
            } else if (key[e] >= lo_thr) {
                unsigned pos = atomicAdd(&s_bn, 1u);
                if (pos < BCAP) {
                    double t = -log((double)uv[e]);
                    double r = (double)fmaxf(wv[e], 1e-30f) / t;   // exact-order key
                    bkey[pos] = (unsigned long long)__double_as_longlong(r);
                    bidx[pos] = 4 * ((e >> 2) * NT + tid) + (e & 3);
                }
            }
        }
        unsigned nv = nhi;
        #pragma unroll
        for (int off = 32; off > 0; off >>= 1) nv += __shfl_down(nv, off, 64);
        if (lane == 0) atomicAdd(&s_nhi, nv);
        __syncthreads();
        need = k - (int)s_nhi;                       // >= 1; bn >= need by construction
        bn = s_bn; if (bn > BCAP) bn = BCAP;
    }

    // ---- Phase 3: selection + float32 outputs ----
    const size_t obase = (size_t)row * L_LEN;
    float* o0 = out + obase;                      // masked ids
    float* o1 = out + (size_t)n_per + obase;      // mask
    float* o2 = out + 2 * (size_t)n_per + obase;  // -mask

    float f0[8], f1[8], f2[8];
    #pragma unroll
    for (int e = 0; e < 8; ++e) {
        bool sel;
        if (key[e] > hi_thr) {
            sel = true;
        } else if (key[e] < lo_thr) {
            sel = false;
        } else {
            // band member: rank by (f64 key desc, index asc) — stable, exact
            double t = -log((double)uv[e]);
            double r = (double)fmaxf(wv[e], 1e-30f) / t;
            unsigned long long myk = (unsigned long long)__double_as_longlong(r);
            int myi = 4 * ((e >> 2) * NT + tid) + (e & 3);
            int rnk = 0;
            for (unsigned j = 0; j < bn; ++j)
                rnk += (bkey[j] > myk) || (bkey[j] == myk && bidx[j] < myi);
            sel = (rnk < need);
        }
        f0[e] = sel ? 103.0f : (float)ida[e];
        f1[e] = sel ? 1.0f : 0.0f;
        f2[e] = sel ? -1.0f : -0.0f;
    }
    reinterpret_cast<float4*>(o0)[tid]      = make_float4(f0[0], f0[1], f0[2], f0[3]);
    reinterpret_cast<float4*>(o0)[NT + tid] = make_float4(f0[4], f0[5], f0[6], f0[7]);
    reinterpret_cast<float4*>(o1)[tid]      = make_float4(f1[0], f1[1], f1[2], f1[3]);
    reinterpret_cast<float4*>(o1)[NT + tid] = make_float4(f1[4], f1[5], f1[6], f1[7]);
    reinterpret_cast<float4*>(o2)[tid]      = make_float4(f2[0], f2[1], f2[2], f2[3]);
    reinterpret_cast<float4*>(o2)[NT + tid] = make_float4(f2[4], f2[5], f2[6], f2[7]);
}

extern "C" void kernel_launch(void* const* d_in, const int* in_sizes, int n_in,
                              void* d_out, int out_size, void* d_ws, size_t ws_size,
                              hipStream_t stream) {
    const int*   ids   = (const int*)d_in[0];     // (B,J,L) ids (int32/int64 auto-detect)
    const float* amask = (const float*)d_in[1];   // (B,J,2L) float32
    const float* uin   = (const float*)d_in[2];   // (B,J,L) float32
    float* out = (float*)d_out;                   // float32 x (3 * B*J*L)

    const int n_per = ROWS * L_LEN;               // 2,097,152 (hardcoded geometry)

    AttentionEssentialReinforce_51238959841470_kernel<<<dim3(ROWS), dim3(NT), 0, stream>>>(
        ids, amask, uin, out, n_per);
}